// Round 10
// baseline (73.512 us; speedup 1.0000x reference)
//
#include <hip/hip_runtime.h>
#include <hip/hip_bf16.h>
#include <math.h>

// QuantumBottle, fully fused single kernel, parallel setup + packed-FP32 phase D.
// out_j = b_j + sum_{m in {1,cos,sin}^4} G_j[m] * prod_w u_w[m_w],
// u_w = (1, cos(theta_w), sin(theta_w)), theta_w = tanh(z_w)*scale.
//
// R10: phase D packed as 2 sample-pairs in v2f (v_pk_fma_f32) -> halves the
// 1440-FMA multilinear evaluation. R4's packed attempt spilled (VGPR 256,
// 56 MB scratch fetch); the R8/R9 structure avoids that: no precomputed e01
// (rebuilt per u-block from c0/s0/c1/s1), per-u scheduling fences bound LDS
// load hoisting. Peak live ~110 VGPR packed.

#define QB_S 4   // samples per thread = 2 packed pairs

typedef float v2f __attribute__((ext_vector_type(2)));

__device__ __forceinline__ float2 qb_cmul(float2 a, float2 b) {
    return make_float2(a.x * b.x - a.y * b.y, a.x * b.y + a.y * b.x);
}

__global__ void __launch_bounds__(256) qb_fused(
    const float* __restrict__ z, const float* __restrict__ scale,
    const float* __restrict__ qw, const float* __restrict__ W,
    const float* __restrict__ bias, float* __restrict__ out, int Bn)
{
    __shared__ float sTrig[8][6];
    __shared__ float2 sU[2][4][2][2];
    __shared__ float2 sV1[16][16];
    __shared__ float2 sU2[16][16];
    __shared__ float Vr[16][16], Vi[16][16];
    __shared__ __align__(16) float4 sM[256];
    __shared__ __align__(16) float sC[81 * 4];

    const int tid = threadIdx.x;

    // ---- A1: trig table (24 threads) ----
    if (tid < 24) {
        const int g = tid / 3, which = tid % 3;
        const float phi = qw[g * 3 + 0], th = qw[g * 3 + 1], om = qw[g * 3 + 2];
        const float ang = (which == 0) ? 0.5f * th
                        : (which == 1) ? 0.5f * (phi + om)
                                       : 0.5f * (phi - om);
        float sn, cs;
        __sincosf(ang, &sn, &cs);
        sTrig[g][2 * which + 0] = cs;
        sTrig[g][2 * which + 1] = sn;
    }
    __syncthreads();

    // ---- A2a: 2x2 Rot gate entries (32 threads) ----
    if (tid < 32) {
        const int l = tid >> 4, w = (tid >> 2) & 3, r = (tid >> 1) & 1, c = tid & 1;
        const int g = l * 4 + w;
        const float ct  = sTrig[g][0], st  = sTrig[g][1];
        const float epr = sTrig[g][2], epi = -sTrig[g][3];
        const float emr = sTrig[g][4], emi = -sTrig[g][5];
        float re, im;
        if (r == 0 && c == 0)      { re =  epr * ct; im =  epi * ct; }
        else if (r == 0)           { re = -emr * st; im =  emi * st; }
        else if (c == 0)           { re =  emr * st; im =  emi * st; }
        else                       { re =  epr * ct; im = -epi * ct; }
        sU[l][w][r][c] = make_float2(re, im);
    }
    __syncthreads();

    // ---- A2b: tensor-product entries for both layers (256 threads) ----
    const int vi = tid >> 4, vk = tid & 15;
    const int i0 = (vi >> 3) & 1, i1 = (vi >> 2) & 1, i2 = (vi >> 1) & 1, i3 = vi & 1;
    const int k0 = (vk >> 3) & 1, k1 = (vk >> 2) & 1, k2 = (vk >> 1) & 1, k3 = vk & 1;
    int b0 = i0, b1 = i1, b2 = i2, b3 = i3;
    b1 ^= b0; b2 ^= b1; b3 ^= b2; b0 ^= b3;          // CNOT-ring permutation
    const int sig = (b0 << 3) | (b1 << 2) | (b2 << 1) | b3;
    {
        const float2 e1 = qb_cmul(qb_cmul(sU[0][0][i0][k0], sU[0][1][i1][k1]),
                                  qb_cmul(sU[0][2][i2][k2], sU[0][3][i3][k3]));
        const float2 e2 = qb_cmul(qb_cmul(sU[1][0][i0][k0], sU[1][1][i1][k1]),
                                  qb_cmul(sU[1][2][i2][k2], sU[1][3][i3][k3]));
        sV1[sig][vk] = e1;
        sU2[vi][vk]  = e2;
    }
    __syncthreads();

    // ---- A2c: V = P * U2 * V1 (16x16 complex matmul, 256 threads) ----
    {
        float accr = 0.f, acci = 0.f;
        #pragma unroll
        for (int m = 0; m < 16; ++m) {
            const float2 u = sU2[vi][m];
            const float2 v = sV1[m][vk];
            accr += u.x * v.x - u.y * v.y;
            acci += u.x * v.y + u.y * v.x;
        }
        Vr[sig][vk] = accr;
        Vi[sig][vk] = acci;
    }
    __syncthreads();

    // ---- B: M_w[k,kp] (256 threads) ----
    {
        const int k = tid >> 4, kp = tid & 15;
        float m0 = 0.f, m1 = 0.f, m2 = 0.f, m3 = 0.f;
        #pragma unroll
        for (int i = 0; i < 16; ++i) {
            const float pr = Vr[i][k] * Vr[i][kp] + Vi[i][k] * Vi[i][kp];
            m0 += ((i >> 3) & 1) ? -pr : pr;
            m1 += ((i >> 2) & 1) ? -pr : pr;
            m2 += ((i >> 1) & 1) ? -pr : pr;
            m3 += ( i       & 1) ? -pr : pr;
        }
        sM[tid] = make_float4(m0, m1, m2, m3);
    }
    __syncthreads();

    // ---- C: G_j[m] over the 3^4 basis (81 threads) ----
    if (tid < 81) {
        const int mm[4] = { tid / 27, (tid / 9) % 3, (tid / 3) % 3, tid % 3 };
        float h0 = 0.f, h1 = 0.f, h2 = 0.f, h3 = 0.f;
        #pragma unroll
        for (int t16 = 0; t16 < 16; ++t16) {
            int k = 0, kp = 0;
            float sgn = 0.0625f;
            #pragma unroll
            for (int w = 0; w < 4; ++w) {
                const int b = (t16 >> (3 - w)) & 1;
                int kw, kpw;
                if (mm[w] == 2) { kw = b; kpw = 1 - b; }
                else            { kw = b; kpw = b; if (mm[w] == 1 && b) sgn = -sgn; }
                k  |= kw  << (3 - w);
                kp |= kpw << (3 - w);
            }
            const float4 mv = sM[k * 16 + kp];
            h0 += sgn * mv.x; h1 += sgn * mv.y; h2 += sgn * mv.z; h3 += sgn * mv.w;
        }
        #pragma unroll
        for (int j = 0; j < 4; ++j) {
            sC[tid * 4 + j] = W[j * 4 + 0] * h0 + W[j * 4 + 1] * h1 +
                              W[j * 4 + 2] * h2 + W[j * 4 + 3] * h3;
        }
    }
    __syncthreads();

    // ---- D: packed multilinear form, 2 sample-pairs per thread ----
    const int g  = blockIdx.x * 256 + tid;
    const float sc = scale[0];
    const float b0_ = bias[0], b1_ = bias[1], b2_ = bias[2], b3_ = bias[3];

    v2f c0[2], s0[2], c1[2], s1[2];
    v2f e23[2][9];
    v2f acc[2][4];
    bool valid[QB_S];

    #pragma unroll
    for (int p = 0; p < 2; ++p) {
        #pragma unroll
        for (int l = 0; l < 2; ++l) {
            const int s = 2 * p + l;
            const int idx = g * QB_S + s;
            valid[s] = (idx < Bn);
            const float4 zv = valid[s] ? reinterpret_cast<const float4*>(z)[idx]
                                       : make_float4(0.f, 0.f, 0.f, 0.f);
            const float zz[4] = { zv.x, zv.y, zv.z, zv.w };
            float c[4], sn[4];
            #pragma unroll
            for (int w = 0; w < 4; ++w) {
                const float x = zz[w];
                const float e = __expf(-2.0f * fabsf(x));
                float t = __fdividef(1.0f - e, 1.0f + e);
                t = copysignf(t, x);
                __sincosf(t * sc, &sn[w], &c[w]);
            }
            const float a23[9] = { 1.0f,  c[3],        sn[3],
                                   c[2],  c[2]*c[3],   c[2]*sn[3],
                                   sn[2], sn[2]*c[3],  sn[2]*sn[3] };
            if (l == 0) {
                c0[p].x = c[0]; s0[p].x = sn[0]; c1[p].x = c[1]; s1[p].x = sn[1];
                #pragma unroll
                for (int v = 0; v < 9; ++v) e23[p][v].x = a23[v];
            } else {
                c0[p].y = c[0]; s0[p].y = sn[0]; c1[p].y = c[1]; s1[p].y = sn[1];
                #pragma unroll
                for (int v = 0; v < 9; ++v) e23[p][v].y = a23[v];
            }
        }
        acc[p][0] = (v2f){b0_, b0_};
        acc[p][1] = (v2f){b1_, b1_};
        acc[p][2] = (v2f){b2_, b2_};
        acc[p][3] = (v2f){b3_, b3_};
    }

    #pragma unroll
    for (int u = 0; u < 9; ++u) {
        v2f e01u[2];
        #pragma unroll
        for (int p = 0; p < 2; ++p) {
            const v2f fa = (u / 3 == 0) ? (v2f){1.f, 1.f} : (u / 3 == 1 ? c0[p] : s0[p]);
            const v2f fb = (u % 3 == 0) ? (v2f){1.f, 1.f} : (u % 3 == 1 ? c1[p] : s1[p]);
            e01u[p] = fa * fb;
        }
        v2f tj[2][4];
        #pragma unroll
        for (int p = 0; p < 2; ++p)
            tj[p][0] = tj[p][1] = tj[p][2] = tj[p][3] = (v2f)0.0f;
        #pragma unroll
        for (int v = 0; v < 9; ++v) {
            const float4 cc = reinterpret_cast<const float4*>(sC)[u * 9 + v];
            #pragma unroll
            for (int p = 0; p < 2; ++p) {
                const v2f ev = e23[p][v];
                tj[p][0] = cc.x * ev + tj[p][0];
                tj[p][1] = cc.y * ev + tj[p][1];
                tj[p][2] = cc.z * ev + tj[p][2];
                tj[p][3] = cc.w * ev + tj[p][3];
            }
        }
        #pragma unroll
        for (int p = 0; p < 2; ++p) {
            acc[p][0] = e01u[p] * tj[p][0] + acc[p][0];
            acc[p][1] = e01u[p] * tj[p][1] + acc[p][1];
            acc[p][2] = e01u[p] * tj[p][2] + acc[p][2];
            acc[p][3] = e01u[p] * tj[p][3] + acc[p][3];
        }
        asm volatile("" ::: "memory");   // bound peak VGPR pressure (anti-spill)
    }

    #pragma unroll
    for (int p = 0; p < 2; ++p) {
        #pragma unroll
        for (int l = 0; l < 2; ++l) {
            const int s = 2 * p + l;
            const int idx = g * QB_S + s;
            if (valid[s]) {
                float4 o;
                if (l == 0) o = make_float4(acc[p][0].x, acc[p][1].x, acc[p][2].x, acc[p][3].x);
                else        o = make_float4(acc[p][0].y, acc[p][1].y, acc[p][2].y, acc[p][3].y);
                reinterpret_cast<float4*>(out)[idx] = o;
            }
        }
    }
}

extern "C" void kernel_launch(void* const* d_in, const int* in_sizes, int n_in,
                              void* d_out, int out_size, void* d_ws, size_t ws_size,
                              hipStream_t stream) {
    const float* z  = (const float*)d_in[0];   // (B,4)
    const float* sc = (const float*)d_in[1];   // scalar
    const float* qw = (const float*)d_in[2];   // (2,4,3)
    const float* W  = (const float*)d_in[3];   // (4,4)
    const float* bb = (const float*)d_in[4];   // (4,)
    float* out = (float*)d_out;

    const int Bn = in_sizes[0] / 4;
    const int threads_total = (Bn + QB_S - 1) / QB_S;
    const int blocks = (threads_total + 255) / 256;

    hipLaunchKernelGGL(qb_fused, dim3(blocks), dim3(256), 0, stream,
                       z, sc, qw, W, bb, out, Bn);
}

// Round 11
// 27.650 us; speedup vs baseline: 2.6587x; 2.6587x over previous
//
#include <hip/hip_runtime.h>
#include <hip/hip_bf16.h>
#include <math.h>

// QuantumBottle, fully fused single kernel, parallel setup (R9 structure).
// out_j = b_j + sum_{m in {1,cos,sin}^4} G_j[m] * prod_w u_w[m_w],
// u_w = (1, cos(theta_w), sin(theta_w)), theta_w = tanh(z_w)*scale.
//
// R11: QB_S=2 -> 1024 blocks = 16 waves/CU (was 8). Occupancy was
// GRID-limited, not VGPR-limited. Scalar FMA only: both packed-v2f
// attempts (R4, R10) spilled to 256 VGPR + ~53 MB scratch traffic.
// tanh via 1 - 2/(e^{2x}+1) (saves fabs/copysign; saturates correctly).

#define QB_S 2   // samples per thread (contiguous)

__device__ __forceinline__ float2 qb_cmul(float2 a, float2 b) {
    return make_float2(a.x * b.x - a.y * b.y, a.x * b.y + a.y * b.x);
}

__global__ void __launch_bounds__(256) qb_fused(
    const float* __restrict__ z, const float* __restrict__ scale,
    const float* __restrict__ qw, const float* __restrict__ W,
    const float* __restrict__ bias, float* __restrict__ out, int Bn)
{
    __shared__ float sTrig[8][6];
    __shared__ float2 sU[2][4][2][2];
    __shared__ float2 sV1[16][16];
    __shared__ float2 sU2[16][16];
    __shared__ float Vr[16][16], Vi[16][16];
    __shared__ __align__(16) float4 sM[256];
    __shared__ __align__(16) float sC[81 * 4];

    const int tid = threadIdx.x;

    // ---- A1: trig table (24 threads) ----
    if (tid < 24) {
        const int g = tid / 3, which = tid % 3;
        const float phi = qw[g * 3 + 0], th = qw[g * 3 + 1], om = qw[g * 3 + 2];
        const float ang = (which == 0) ? 0.5f * th
                        : (which == 1) ? 0.5f * (phi + om)
                                       : 0.5f * (phi - om);
        float sn, cs;
        __sincosf(ang, &sn, &cs);
        sTrig[g][2 * which + 0] = cs;
        sTrig[g][2 * which + 1] = sn;
    }
    __syncthreads();

    // ---- A2a: 2x2 Rot gate entries (32 threads) ----
    if (tid < 32) {
        const int l = tid >> 4, w = (tid >> 2) & 3, r = (tid >> 1) & 1, c = tid & 1;
        const int g = l * 4 + w;
        const float ct  = sTrig[g][0], st  = sTrig[g][1];
        const float epr = sTrig[g][2], epi = -sTrig[g][3];
        const float emr = sTrig[g][4], emi = -sTrig[g][5];
        float re, im;
        if (r == 0 && c == 0)      { re =  epr * ct; im =  epi * ct; }
        else if (r == 0)           { re = -emr * st; im =  emi * st; }
        else if (c == 0)           { re =  emr * st; im =  emi * st; }
        else                       { re =  epr * ct; im = -epi * ct; }
        sU[l][w][r][c] = make_float2(re, im);
    }
    __syncthreads();

    // ---- A2b: tensor-product entries for both layers (256 threads) ----
    const int vi = tid >> 4, vk = tid & 15;
    const int i0 = (vi >> 3) & 1, i1 = (vi >> 2) & 1, i2 = (vi >> 1) & 1, i3 = vi & 1;
    const int k0 = (vk >> 3) & 1, k1 = (vk >> 2) & 1, k2 = (vk >> 1) & 1, k3 = vk & 1;
    int b0 = i0, b1 = i1, b2 = i2, b3 = i3;
    b1 ^= b0; b2 ^= b1; b3 ^= b2; b0 ^= b3;          // CNOT-ring permutation
    const int sig = (b0 << 3) | (b1 << 2) | (b2 << 1) | b3;
    {
        const float2 e1 = qb_cmul(qb_cmul(sU[0][0][i0][k0], sU[0][1][i1][k1]),
                                  qb_cmul(sU[0][2][i2][k2], sU[0][3][i3][k3]));
        const float2 e2 = qb_cmul(qb_cmul(sU[1][0][i0][k0], sU[1][1][i1][k1]),
                                  qb_cmul(sU[1][2][i2][k2], sU[1][3][i3][k3]));
        sV1[sig][vk] = e1;
        sU2[vi][vk]  = e2;
    }
    __syncthreads();

    // ---- A2c: V = P * U2 * V1 (16x16 complex matmul, 256 threads) ----
    {
        float accr = 0.f, acci = 0.f;
        #pragma unroll
        for (int m = 0; m < 16; ++m) {
            const float2 u = sU2[vi][m];
            const float2 v = sV1[m][vk];
            accr += u.x * v.x - u.y * v.y;
            acci += u.x * v.y + u.y * v.x;
        }
        Vr[sig][vk] = accr;
        Vi[sig][vk] = acci;
    }
    __syncthreads();

    // ---- B: M_w[k,kp] (256 threads) ----
    {
        const int k = tid >> 4, kp = tid & 15;
        float m0 = 0.f, m1 = 0.f, m2 = 0.f, m3 = 0.f;
        #pragma unroll
        for (int i = 0; i < 16; ++i) {
            const float pr = Vr[i][k] * Vr[i][kp] + Vi[i][k] * Vi[i][kp];
            m0 += ((i >> 3) & 1) ? -pr : pr;
            m1 += ((i >> 2) & 1) ? -pr : pr;
            m2 += ((i >> 1) & 1) ? -pr : pr;
            m3 += ( i       & 1) ? -pr : pr;
        }
        sM[tid] = make_float4(m0, m1, m2, m3);
    }
    __syncthreads();

    // ---- C: G_j[m] over the 3^4 basis (81 threads) ----
    if (tid < 81) {
        const int mm[4] = { tid / 27, (tid / 9) % 3, (tid / 3) % 3, tid % 3 };
        float h0 = 0.f, h1 = 0.f, h2 = 0.f, h3 = 0.f;
        #pragma unroll
        for (int t16 = 0; t16 < 16; ++t16) {
            int k = 0, kp = 0;
            float sgn = 0.0625f;
            #pragma unroll
            for (int w = 0; w < 4; ++w) {
                const int b = (t16 >> (3 - w)) & 1;
                int kw, kpw;
                if (mm[w] == 2) { kw = b; kpw = 1 - b; }
                else            { kw = b; kpw = b; if (mm[w] == 1 && b) sgn = -sgn; }
                k  |= kw  << (3 - w);
                kp |= kpw << (3 - w);
            }
            const float4 mv = sM[k * 16 + kp];
            h0 += sgn * mv.x; h1 += sgn * mv.y; h2 += sgn * mv.z; h3 += sgn * mv.w;
        }
        #pragma unroll
        for (int j = 0; j < 4; ++j) {
            sC[tid * 4 + j] = W[j * 4 + 0] * h0 + W[j * 4 + 1] * h1 +
                              W[j * 4 + 2] * h2 + W[j * 4 + 3] * h3;
        }
    }
    __syncthreads();

    // ---- D: multilinear form, QB_S contiguous samples per thread ----
    const int g  = blockIdx.x * 256 + tid;
    const float sc = scale[0];
    const float b0_ = bias[0], b1_ = bias[1], b2_ = bias[2], b3_ = bias[3];

    float c0[QB_S], s0[QB_S], c1[QB_S], s1[QB_S];
    float e23[QB_S][9];
    float acc[QB_S][4];
    bool valid[QB_S];

    #pragma unroll
    for (int s = 0; s < QB_S; ++s) {
        const int idx = g * QB_S + s;
        valid[s] = (idx < Bn);
        const float4 zv = valid[s] ? reinterpret_cast<const float4*>(z)[idx]
                                   : make_float4(0.f, 0.f, 0.f, 0.f);
        const float zz[4] = { zv.x, zv.y, zv.z, zv.w };
        float c[4], sn[4];
        #pragma unroll
        for (int w = 0; w < 4; ++w) {
            const float x = zz[w];
            // tanh(x) = 1 - 2/(e^{2x}+1); saturates correctly as e->0/inf.
            const float e = __expf(2.0f * x);
            const float t = 1.0f - __fdividef(2.0f, e + 1.0f);
            __sincosf(t * sc, &sn[w], &c[w]);
        }
        c0[s] = c[0]; s0[s] = sn[0]; c1[s] = c[1]; s1[s] = sn[1];
        e23[s][0] = 1.0f;  e23[s][1] = c[3];          e23[s][2] = sn[3];
        e23[s][3] = c[2];  e23[s][4] = c[2] * c[3];   e23[s][5] = c[2] * sn[3];
        e23[s][6] = sn[2]; e23[s][7] = sn[2] * c[3];  e23[s][8] = sn[2] * sn[3];
        acc[s][0] = b0_; acc[s][1] = b1_; acc[s][2] = b2_; acc[s][3] = b3_;
    }

    #pragma unroll
    for (int u = 0; u < 9; ++u) {
        float e01u[QB_S];
        #pragma unroll
        for (int s = 0; s < QB_S; ++s) {
            const float fa = (u / 3 == 0) ? 1.0f : (u / 3 == 1 ? c0[s] : s0[s]);
            const float fb = (u % 3 == 0) ? 1.0f : (u % 3 == 1 ? c1[s] : s1[s]);
            e01u[s] = fa * fb;
        }
        float tj[QB_S][4];
        #pragma unroll
        for (int s = 0; s < QB_S; ++s)
            tj[s][0] = tj[s][1] = tj[s][2] = tj[s][3] = 0.0f;
        #pragma unroll
        for (int v = 0; v < 9; ++v) {
            const float4 cc = reinterpret_cast<const float4*>(sC)[u * 9 + v];
            #pragma unroll
            for (int s = 0; s < QB_S; ++s) {
                const float ev = e23[s][v];
                tj[s][0] = fmaf(cc.x, ev, tj[s][0]);
                tj[s][1] = fmaf(cc.y, ev, tj[s][1]);
                tj[s][2] = fmaf(cc.z, ev, tj[s][2]);
                tj[s][3] = fmaf(cc.w, ev, tj[s][3]);
            }
        }
        #pragma unroll
        for (int s = 0; s < QB_S; ++s) {
            acc[s][0] = fmaf(e01u[s], tj[s][0], acc[s][0]);
            acc[s][1] = fmaf(e01u[s], tj[s][1], acc[s][1]);
            acc[s][2] = fmaf(e01u[s], tj[s][2], acc[s][2]);
            acc[s][3] = fmaf(e01u[s], tj[s][3], acc[s][3]);
        }
        asm volatile("" ::: "memory");   // bound peak VGPR pressure (anti-spill)
    }

    #pragma unroll
    for (int s = 0; s < QB_S; ++s) {
        const int idx = g * QB_S + s;
        if (valid[s])
            reinterpret_cast<float4*>(out)[idx] =
                make_float4(acc[s][0], acc[s][1], acc[s][2], acc[s][3]);
    }
}

extern "C" void kernel_launch(void* const* d_in, const int* in_sizes, int n_in,
                              void* d_out, int out_size, void* d_ws, size_t ws_size,
                              hipStream_t stream) {
    const float* z  = (const float*)d_in[0];   // (B,4)
    const float* sc = (const float*)d_in[1];   // scalar
    const float* qw = (const float*)d_in[2];   // (2,4,3)
    const float* W  = (const float*)d_in[3];   // (4,4)
    const float* bb = (const float*)d_in[4];   // (4,)
    float* out = (float*)d_out;

    const int Bn = in_sizes[0] / 4;
    const int threads_total = (Bn + QB_S - 1) / QB_S;
    const int blocks = (threads_total + 255) / 256;

    hipLaunchKernelGGL(qb_fused, dim3(blocks), dim3(256), 0, stream,
                       z, sc, qw, W, bb, out, Bn);
}

// Round 12
// 17.346 us; speedup vs baseline: 4.2379x; 1.5940x over previous
//
#include <hip/hip_runtime.h>
#include <hip/hip_bf16.h>
#include <math.h>

// QuantumBottle, fused single kernel; phase D on the MATRIX CORE.
// out[b][j] = bias_j + sum_{m<81} E[b][m] * G[j][m],
//   E[b] = e01 (x) e23 basis from theta_w = tanh(z_w)*scale,
//   G    = 81x4 coefficient table built per block (phases A-C, verified R2-R11).
// Phase D: per wave, each lane builds its own sample's E (f32->bf16), writes a
// wave-private LDS panel [64][104] bf16 (no barriers), then 4 MFMA passes
// (mfma_f32_16x16x32_bf16, K=96 zero-padded, N=16 samples) with G split into
// bf16 hi+lo (6 MFMAs/pass) for precision. D-layout: lanes 0-15 hold the full
// float4 output of one sample -> coalesced store.

typedef __attribute__((ext_vector_type(8))) short bf16x8;
typedef __attribute__((ext_vector_type(4))) float f32x4;

__device__ __forceinline__ float2 qb_cmul(float2 a, float2 b) {
    return make_float2(a.x * b.x - a.y * b.y, a.x * b.y + a.y * b.x);
}

__device__ __forceinline__ unsigned qb_pk(float a, float b) {
    union { __hip_bfloat16 h; unsigned short u; } A, B;
    A.h = __float2bfloat16(a);
    B.h = __float2bfloat16(b);
    return (unsigned)A.u | ((unsigned)B.u << 16);
}

__global__ void __launch_bounds__(256) qb_fused(
    const float* __restrict__ z, const float* __restrict__ scale,
    const float* __restrict__ qw, const float* __restrict__ W,
    const float* __restrict__ bias, float* __restrict__ out, int Bn)
{
    // LDS pool: setup tables (10688 B) overlaid by phase-D E panels (53248 B).
    __shared__ __align__(16) char shpool[53248];
    __shared__ __align__(16) float sC[81 * 4];
    __shared__ __align__(16) unsigned short sGbH[4][96];
    __shared__ __align__(16) unsigned short sGbL[4][96];

    float  (*sTrig)[6]  = (float(*)[6])  (shpool);          // 192 B
    float2  *sU         = (float2*)      (shpool + 192);    // 256 B
    float2 (*sV1)[16]   = (float2(*)[16])(shpool + 448);    // 2048 B
    float2 (*sU2)[16]   = (float2(*)[16])(shpool + 2496);   // 2048 B
    float  (*Vr)[16]    = (float(*)[16]) (shpool + 4544);   // 1024 B
    float  (*Vi)[16]    = (float(*)[16]) (shpool + 5568);   // 1024 B
    float4  *sM         = (float4*)      (shpool + 6592);   // 4096 B -> 10688
    unsigned short *Eb  = (unsigned short*)shpool;          // phase D: [4][64][104]

    const int tid = threadIdx.x;

    // ---- A1: trig table (24 threads) ----
    if (tid < 24) {
        const int g = tid / 3, which = tid % 3;
        const float phi = qw[g * 3 + 0], th = qw[g * 3 + 1], om = qw[g * 3 + 2];
        const float ang = (which == 0) ? 0.5f * th
                        : (which == 1) ? 0.5f * (phi + om)
                                       : 0.5f * (phi - om);
        float sn, cs;
        __sincosf(ang, &sn, &cs);
        sTrig[g][2 * which + 0] = cs;
        sTrig[g][2 * which + 1] = sn;
    }
    __syncthreads();

    // ---- A2a: 2x2 Rot gate entries (32 threads) ----
    if (tid < 32) {
        const int l = tid >> 4, w = (tid >> 2) & 3, r = (tid >> 1) & 1, c = tid & 1;
        const int g = l * 4 + w;
        const float ct  = sTrig[g][0], st  = sTrig[g][1];
        const float epr = sTrig[g][2], epi = -sTrig[g][3];
        const float emr = sTrig[g][4], emi = -sTrig[g][5];
        float re, im;
        if (r == 0 && c == 0)      { re =  epr * ct; im =  epi * ct; }
        else if (r == 0)           { re = -emr * st; im =  emi * st; }
        else if (c == 0)           { re =  emr * st; im =  emi * st; }
        else                       { re =  epr * ct; im = -epi * ct; }
        sU[((l * 4 + w) * 2 + r) * 2 + c] = make_float2(re, im);
    }
    __syncthreads();

    // ---- A2b: tensor-product entries for both layers (256 threads) ----
    const int vi = tid >> 4, vk = tid & 15;
    {
        const int i0 = (vi >> 3) & 1, i1 = (vi >> 2) & 1, i2 = (vi >> 1) & 1, i3 = vi & 1;
        const int k0 = (vk >> 3) & 1, k1 = (vk >> 2) & 1, k2 = (vk >> 1) & 1, k3 = vk & 1;
        int b0 = i0, b1 = i1, b2 = i2, b3 = i3;
        b1 ^= b0; b2 ^= b1; b3 ^= b2; b0 ^= b3;          // CNOT-ring permutation
        const int sig = (b0 << 3) | (b1 << 2) | (b2 << 1) | b3;
        const float2 e1 = qb_cmul(qb_cmul(sU[(0*4+0)*4 + i0*2 + k0], sU[(0*4+1)*4 + i1*2 + k1]),
                                  qb_cmul(sU[(0*4+2)*4 + i2*2 + k2], sU[(0*4+3)*4 + i3*2 + k3]));
        const float2 e2 = qb_cmul(qb_cmul(sU[(1*4+0)*4 + i0*2 + k0], sU[(1*4+1)*4 + i1*2 + k1]),
                                  qb_cmul(sU[(1*4+2)*4 + i2*2 + k2], sU[(1*4+3)*4 + i3*2 + k3]));
        sV1[sig][vk] = e1;
        sU2[vi][vk]  = e2;
    }
    __syncthreads();

    // ---- A2c: V = P * U2 * V1 (16x16 complex matmul, 256 threads) ----
    {
        const int i0 = (vi >> 3) & 1, i1 = (vi >> 2) & 1, i2 = (vi >> 1) & 1, i3 = vi & 1;
        int b0 = i0, b1 = i1, b2 = i2, b3 = i3;
        b1 ^= b0; b2 ^= b1; b3 ^= b2; b0 ^= b3;
        const int sig = (b0 << 3) | (b1 << 2) | (b2 << 1) | b3;
        float accr = 0.f, acci = 0.f;
        #pragma unroll
        for (int m = 0; m < 16; ++m) {
            const float2 u = sU2[vi][m];
            const float2 v = sV1[m][vk];
            accr += u.x * v.x - u.y * v.y;
            acci += u.x * v.y + u.y * v.x;
        }
        Vr[sig][vk] = accr;
        Vi[sig][vk] = acci;
    }
    __syncthreads();

    // ---- B: M_w[k,kp] (256 threads) ----
    {
        const int k = tid >> 4, kp = tid & 15;
        float m0 = 0.f, m1 = 0.f, m2 = 0.f, m3 = 0.f;
        #pragma unroll
        for (int i = 0; i < 16; ++i) {
            const float pr = Vr[i][k] * Vr[i][kp] + Vi[i][k] * Vi[i][kp];
            m0 += ((i >> 3) & 1) ? -pr : pr;
            m1 += ((i >> 2) & 1) ? -pr : pr;
            m2 += ((i >> 1) & 1) ? -pr : pr;
            m3 += ( i       & 1) ? -pr : pr;
        }
        sM[tid] = make_float4(m0, m1, m2, m3);
    }
    __syncthreads();

    // ---- C: G_j[m] over the 3^4 basis (81 threads) ----
    if (tid < 81) {
        const int mm[4] = { tid / 27, (tid / 9) % 3, (tid / 3) % 3, tid % 3 };
        float h0 = 0.f, h1 = 0.f, h2 = 0.f, h3 = 0.f;
        #pragma unroll
        for (int t16 = 0; t16 < 16; ++t16) {
            int k = 0, kp = 0;
            float sgn = 0.0625f;
            #pragma unroll
            for (int w = 0; w < 4; ++w) {
                const int b = (t16 >> (3 - w)) & 1;
                int kw, kpw;
                if (mm[w] == 2) { kw = b; kpw = 1 - b; }
                else            { kw = b; kpw = b; if (mm[w] == 1 && b) sgn = -sgn; }
                k  |= kw  << (3 - w);
                kp |= kpw << (3 - w);
            }
            const float4 mv = sM[k * 16 + kp];
            h0 += sgn * mv.x; h1 += sgn * mv.y; h2 += sgn * mv.z; h3 += sgn * mv.w;
        }
        #pragma unroll
        for (int j = 0; j < 4; ++j) {
            sC[tid * 4 + j] = W[j * 4 + 0] * h0 + W[j * 4 + 1] * h1 +
                              W[j * 4 + 2] * h2 + W[j * 4 + 3] * h3;
        }
    }
    __syncthreads();

    // ---- C2: bf16 hi/lo split G tables, K padded to 96 (96 threads) ----
    if (tid < 96) {
        #pragma unroll
        for (int j = 0; j < 4; ++j) {
            float gv = (tid < 81) ? sC[tid * 4 + j] : 0.0f;
            union { __hip_bfloat16 h; unsigned short u; } H, L;
            H.h = __float2bfloat16(gv);
            float hi = __bfloat162float(H.h);
            L.h = __float2bfloat16(gv - hi);
            sGbH[j][tid] = H.u;
            sGbL[j][tid] = L.u;
        }
    }
    __syncthreads();   // also orders all setup-table reads before Eb overwrites

    // ---- D: MFMA multilinear evaluation ----
    const int lane = tid & 63, wid = tid >> 6;
    const int fm = lane & 15, koct = lane >> 4;

    bf16x8 aH0 = {0,0,0,0,0,0,0,0}, aH1 = aH0, aH2 = aH0;
    bf16x8 aL0 = aH0, aL1 = aH0, aL2 = aH0;
    if (fm < 4) {
        aH0 = *reinterpret_cast<const bf16x8*>(&sGbH[fm][ 0 + koct * 8]);
        aH1 = *reinterpret_cast<const bf16x8*>(&sGbH[fm][32 + koct * 8]);
        aH2 = *reinterpret_cast<const bf16x8*>(&sGbH[fm][64 + koct * 8]);
        aL0 = *reinterpret_cast<const bf16x8*>(&sGbL[fm][ 0 + koct * 8]);
        aL1 = *reinterpret_cast<const bf16x8*>(&sGbL[fm][32 + koct * 8]);
        aL2 = *reinterpret_cast<const bf16x8*>(&sGbL[fm][64 + koct * 8]);
    }
    const float sc = scale[0];
    f32x4 biasv;
    biasv[0] = bias[0]; biasv[1] = bias[1]; biasv[2] = bias[2]; biasv[3] = bias[3];

    unsigned short* ebw = Eb + (wid * 64) * 104;       // wave-private panel
    const int base = blockIdx.x * 1024 + wid * 256;

    #pragma unroll 1
    for (int sp = 0; sp < 4; ++sp) {
        const int s0 = base + sp * 64;
        const int myIdx = s0 + lane;
        const float4 zv = (myIdx < Bn) ? reinterpret_cast<const float4*>(z)[myIdx]
                                       : make_float4(0.f, 0.f, 0.f, 0.f);
        const float zz[4] = { zv.x, zv.y, zv.z, zv.w };
        float c[4], sn[4];
        #pragma unroll
        for (int w = 0; w < 4; ++w) {
            const float e = __expf(2.0f * zz[w]);
            const float t = 1.0f - __fdividef(2.0f, e + 1.0f);   // tanh
            __sincosf(t * sc, &sn[w], &c[w]);
        }
        const float e01[9] = { 1.0f,  c[1],        sn[1],
                               c[0],  c[0]*c[1],   c[0]*sn[1],
                               sn[0], sn[0]*c[1],  sn[0]*sn[1] };
        const float e23[9] = { 1.0f,  c[3],        sn[3],
                               c[2],  c[2]*c[3],   c[2]*sn[3],
                               sn[2], sn[2]*c[3],  sn[2]*sn[3] };

        uint4* rowv = reinterpret_cast<uint4*>(ebw + lane * 104);
        #pragma unroll
        for (int oct = 0; oct < 10; ++oct) {
            float E[8];
            #pragma unroll
            for (int e = 0; e < 8; ++e) {
                const int mm = oct * 8 + e;              // < 80, compile-time
                E[e] = e01[mm / 9] * e23[mm % 9];
            }
            rowv[oct] = make_uint4(qb_pk(E[0], E[1]), qb_pk(E[2], E[3]),
                                   qb_pk(E[4], E[5]), qb_pk(E[6], E[7]));
        }
        rowv[10] = make_uint4(qb_pk(e01[8] * e23[8], 0.f), 0u, 0u, 0u);  // m=80
        rowv[11] = make_uint4(0u, 0u, 0u, 0u);                            // pad

        #pragma unroll
        for (int p = 0; p < 4; ++p) {
            const unsigned short* br = ebw + (p * 16 + fm) * 104;
            const bf16x8 b0v = *reinterpret_cast<const bf16x8*>(br +  0 + koct * 8);
            const bf16x8 b1v = *reinterpret_cast<const bf16x8*>(br + 32 + koct * 8);
            const bf16x8 b2v = *reinterpret_cast<const bf16x8*>(br + 64 + koct * 8);
            f32x4 acc = biasv;
            acc = __builtin_amdgcn_mfma_f32_16x16x32_bf16(aH0, b0v, acc, 0, 0, 0);
            acc = __builtin_amdgcn_mfma_f32_16x16x32_bf16(aH1, b1v, acc, 0, 0, 0);
            acc = __builtin_amdgcn_mfma_f32_16x16x32_bf16(aH2, b2v, acc, 0, 0, 0);
            acc = __builtin_amdgcn_mfma_f32_16x16x32_bf16(aL0, b0v, acc, 0, 0, 0);
            acc = __builtin_amdgcn_mfma_f32_16x16x32_bf16(aL1, b1v, acc, 0, 0, 0);
            acc = __builtin_amdgcn_mfma_f32_16x16x32_bf16(aL2, b2v, acc, 0, 0, 0);
            if (koct == 0) {
                const int oidx = s0 + p * 16 + lane;     // lane = fm < 16 here
                if (oidx < Bn)
                    reinterpret_cast<float4*>(out)[oidx] =
                        make_float4(acc[0], acc[1], acc[2], acc[3]);
            }
        }
        asm volatile("" ::: "memory");
    }
}

extern "C" void kernel_launch(void* const* d_in, const int* in_sizes, int n_in,
                              void* d_out, int out_size, void* d_ws, size_t ws_size,
                              hipStream_t stream) {
    const float* z  = (const float*)d_in[0];   // (B,4)
    const float* sc = (const float*)d_in[1];   // scalar
    const float* qw = (const float*)d_in[2];   // (2,4,3)
    const float* W  = (const float*)d_in[3];   // (4,4)
    const float* bb = (const float*)d_in[4];   // (4,)
    float* out = (float*)d_out;

    const int Bn = in_sizes[0] / 4;
    const int blocks = (Bn + 1023) / 1024;     // 1024 samples per block

    hipLaunchKernelGGL(qb_fused, dim3(blocks), dim3(256), 0, stream,
                       z, sc, qw, W, bb, out, Bn);
}